// Round 17
// baseline (2918.312 us; speedup 1.0000x reference)
//
#include <hip/hip_runtime.h>
#include <math.h>
#include <stdint.h>

#define TT 500
#define B2 32
#define FF 240
#define HH 512
#define G2 1024
#define MROWS (TT*B2)   // 16000
#define REC_WGS 8
// flags: one u32 per (step, group, member), strided 16 u32 (64B)
#define FLAG_STRIDE 16
#define FLAGS_PER_LAYER (TT*8*FLAG_STRIDE)

typedef __attribute__((ext_vector_type(8))) short bf16x8;
typedef __attribute__((ext_vector_type(4))) short bf16x4;
typedef __attribute__((ext_vector_type(4))) float f32x4;
typedef unsigned long long u64;

typedef __attribute__((address_space(1))) const unsigned int GU32;
typedef __attribute__((address_space(3))) unsigned int LU32;

static __device__ __forceinline__ unsigned short f2bf(float f) {
    union { float f; unsigned u; } v; v.f = f;
    unsigned r = v.u + 0x7FFFu + ((v.u >> 16) & 1u);
    return (unsigned short)(r >> 16);
}

static __device__ __forceinline__ void gload_lds16(const void* g, void* l) {
    __builtin_amdgcn_global_load_lds((GU32*)g, (LU32*)l, 16, 0, 0);
}

// ---------------- zero flags ----------------
__global__ void zero_cnt(unsigned int* cnt) {
    cnt[blockIdx.x * 256 + threadIdx.x] = 0u;
}

// ---------------- conversion kernels ----------------
// x (B,T,F) fp32 -> A0 bf16 [16000][256] with x2 gather, zero-pad K 240->256
__global__ __launch_bounds__(256)
void cvt_a0(const float* __restrict__ x, unsigned short* __restrict__ A0)
{
    const int idx = blockIdx.x * 256 + threadIdx.x;   // 512000
    const int m = idx >> 5;
    const int k = (idx & 31) * 8;
    const int t = m >> 5, b2 = m & 31;
    bf16x8 o = {0,0,0,0,0,0,0,0};
    if (k < FF) {
        const float* p = (b2 < 16)
            ? x + ((size_t)(b2 * TT + t)) * FF + k
            : x + ((size_t)((b2 - 16) * TT + (TT - 1 - t))) * FF + k;
        f32x4 a = *(const f32x4*)p;
        f32x4 b = *(const f32x4*)(p + 4);
        #pragma unroll
        for (int j = 0; j < 4; ++j) { o[j] = (short)f2bf(a[j]); o[4+j] = (short)f2bf(b[j]); }
    }
    *(bf16x8*)(A0 + (size_t)m * 256 + k) = o;
}

// Ww fp32 [R][Kin] -> bf16 [R][Kout], zero-pad
template<int Kin, int Kout>
__global__ __launch_bounds__(256)
void cvt_pad(const float* __restrict__ src, unsigned short* __restrict__ dst)
{
    const int idx = blockIdx.x * 256 + threadIdx.x;
    const int r = idx / (Kout / 8);
    const int k = (idx % (Kout / 8)) * 8;
    bf16x8 o = {0,0,0,0,0,0,0,0};
    if (k + 8 <= Kin) {
        f32x4 a = *(const f32x4*)(src + (size_t)r * Kin + k);
        f32x4 b = *(const f32x4*)(src + (size_t)r * Kin + k + 4);
        #pragma unroll
        for (int j = 0; j < 4; ++j) { o[j] = (short)f2bf(a[j]); o[4+j] = (short)f2bf(b[j]); }
    }
    *(bf16x8*)(dst + (size_t)r * Kout + k) = o;
}

// ---------------- MFMA GEMM: C[m][n] = sum_k A[m][k]*B[n][k], C fp32 [M][1024] ----------------
template<int K>
__global__ __launch_bounds__(256, 2)
void mfma_gemm(const unsigned short* __restrict__ A,
               const unsigned short* __restrict__ B,
               float* __restrict__ C)
{
    __shared__ alignas(16) char As[16384];
    __shared__ alignas(16) char Bs[16384];
    const int tid = threadIdx.x;
    const int wv = tid >> 6, l = tid & 63, l15 = l & 15, lg = l >> 4;
    const int m0 = blockIdx.x * 128, n0 = blockIdx.y * 128;
    const int wr = wv >> 1, wc = wv & 1;
    f32x4 acc[4][4];
    #pragma unroll
    for (int i = 0; i < 4; ++i)
        #pragma unroll
        for (int j = 0; j < 4; ++j) acc[i][j] = (f32x4){0.f, 0.f, 0.f, 0.f};

    for (int ko = 0; ko < K; ko += 64) {
        #pragma unroll
        for (int i = 0; i < 4; ++i) {
            const int ch = tid + i * 256;          // 0..1023
            const int row = ch >> 3, q = ch & 7;
            const int kb = (q * 16) ^ ((row & 7) << 4);   // byte offset, pre-swizzled source
            gload_lds16(A + (size_t)(m0 + row) * K + ko + (kb >> 1), As + ch * 16);
            gload_lds16(B + (size_t)(n0 + row) * K + ko + (kb >> 1), Bs + ch * 16);
        }
        __syncthreads();
        #pragma unroll
        for (int ks = 0; ks < 2; ++ks) {
            bf16x8 af[4], bf[4];
            #pragma unroll
            for (int ib = 0; ib < 4; ++ib) {
                const int r = wr * 64 + ib * 16 + l15;
                const int sz = (r & 7) << 4;
                const int kb0 = ks * 64 + lg * 8;
                bf16x4 lo = *(const bf16x4*)(As + r * 128 + (kb0 ^ sz));
                bf16x4 hi = *(const bf16x4*)(As + r * 128 + ((kb0 + 32) ^ sz));
                bf16x8 f;
                f[0]=lo[0]; f[1]=lo[1]; f[2]=lo[2]; f[3]=lo[3];
                f[4]=hi[0]; f[5]=hi[1]; f[6]=hi[2]; f[7]=hi[3];
                af[ib] = f;
            }
            #pragma unroll
            for (int jb = 0; jb < 4; ++jb) {
                const int r = wc * 64 + jb * 16 + l15;
                const int sz = (r & 7) << 4;
                const int kb0 = ks * 64 + lg * 8;
                bf16x4 lo = *(const bf16x4*)(Bs + r * 128 + (kb0 ^ sz));
                bf16x4 hi = *(const bf16x4*)(Bs + r * 128 + ((kb0 + 32) ^ sz));
                bf16x8 f;
                f[0]=lo[0]; f[1]=lo[1]; f[2]=lo[2]; f[3]=lo[3];
                f[4]=hi[0]; f[5]=hi[1]; f[6]=hi[2]; f[7]=hi[3];
                bf[jb] = f;
            }
            #pragma unroll
            for (int ib = 0; ib < 4; ++ib)
                #pragma unroll
                for (int jb = 0; jb < 4; ++jb)
                    acc[ib][jb] = __builtin_amdgcn_mfma_f32_16x16x32_bf16(af[ib], bf[jb], acc[ib][jb], 0, 0, 0);
        }
        __syncthreads();
    }
    #pragma unroll
    for (int ib = 0; ib < 4; ++ib)
        #pragma unroll
        for (int jb = 0; jb < 4; ++jb)
            #pragma unroll
            for (int rr = 0; rr < 4; ++rr)
                C[(size_t)(m0 + wr * 64 + ib * 16 + lg * 4 + rr) * G2 +
                  (n0 + wc * 64 + jb * 16 + l15)] = acc[ib][jb][rr];
}

// ---------------- BatchNorm stats ----------------
__global__ __launch_bounds__(256)
void stats_partial(const float* __restrict__ w, float* __restrict__ partS,
                   float* __restrict__ partQ)
{
    const int col = blockIdx.x * 256 + threadIdx.x;
    const int row0 = blockIdx.y * 128;
    float s = 0.f, q = 0.f;
    for (int r = 0; r < 128; ++r) {
        float v = w[(size_t)(row0 + r) * G2 + col];
        s += v; q += v * v;
    }
    partS[blockIdx.y * G2 + col] = s;
    partQ[blockIdx.y * G2 + col] = q;
}

__global__ __launch_bounds__(256)
void stats_final(const float* __restrict__ partS, const float* __restrict__ partQ,
                 const float* __restrict__ gamma, const float* __restrict__ beta,
                 float* __restrict__ scale, float* __restrict__ shift)
{
    const int col = blockIdx.x * 256 + threadIdx.x;
    float s = 0.f, q = 0.f;
    for (int i = 0; i < 125; ++i) { s += partS[i * G2 + col]; q += partQ[i * G2 + col]; }
    const float mean = s * (1.f / 16000.f);
    float var = q * (1.f / 16000.f) - mean * mean;
    var = fmaxf(var, 0.f);
    const float sc = gamma[col] * rsqrtf(var + 1e-5f);
    scale[col] = sc;
    shift[col] = beta[col] - mean * sc;
}

// ---------------- persistent MFMA recurrence: 2 independent groups x 4 WGs ----------------
// R16 base (best measured). Single change: c2 barrier + tid0 flag-RMW replaced
// by PER-WAVE release — after c1 and the publish store, each wave waits only
// its own vmcnt(0) and lane 0 adds 1 to the WG flag; consumers poll for ==8.
// flag==8 implies all 8 waves' publish stores are at the IC (each add is
// program-ordered after that wave's drained stores).
template<int LAYER>
__global__ __launch_bounds__(512, 2)
void rec_kernel(const float* __restrict__ w, const float* __restrict__ scale,
                const float* __restrict__ shift, const float* __restrict__ Wu,
                void* __restrict__ outp, u64* __restrict__ hx,
                unsigned int* __restrict__ flags)
{
    __shared__ alignas(16) char hbuf[2][16384];   // ping-pong h: 16 rows x 1024B, swizzled

    const int g   = blockIdx.x;               // 0..7
    const int d   = g >> 2;                   // group (0 fwd, 1 bwd)
    const int q   = g & 3;                    // member in group
    const int tid = threadIdx.x;
    const int wv  = tid >> 6;
    const int l   = tid & 63;
    const int l15 = l & 15;
    const int lg  = l >> 4;
    const int jcol = 128 * q + 16 * wv + l15; // h column in [128q, 128q+128)

    u64* hx_d = hx + (size_t)d * 4096;        // group region: 2 slots x 2048 u64

    // ---- preload Wu as bf16 B-fragments (k = ks*32 + lg*4 + j, +16 for hi) ----
    bf16x8 bfa[16], bfz[16];
    {
        const float* pa = Wu + (size_t)jcol * HH;
        const float* pz = Wu + (size_t)(HH + jcol) * HH;
        #pragma unroll
        for (int ks = 0; ks < 16; ++ks) {
            f32x4 a0 = *(const f32x4*)(pa + ks * 32 + lg * 4);
            f32x4 a1 = *(const f32x4*)(pa + ks * 32 + lg * 4 + 16);
            f32x4 z0 = *(const f32x4*)(pz + ks * 32 + lg * 4);
            f32x4 z1 = *(const f32x4*)(pz + ks * 32 + lg * 4 + 16);
            bf16x8 fa, fz;
            #pragma unroll
            for (int j = 0; j < 4; ++j) {
                fa[j]     = (short)f2bf(a0[j]);
                fa[4 + j] = (short)f2bf(a1[j]);
                fz[j]     = (short)f2bf(z0[j]);
                fz[4 + j] = (short)f2bf(z1[j]);
            }
            bfa[ks] = fa; bfz[ks] = fz;
        }
    }
    const float scl_a = scale[jcol],      sh_a = shift[jcol];
    const float scl_z = scale[HH + jcol], sh_z = shift[HH + jcol];

    float hold[4] = {0.f, 0.f, 0.f, 0.f};

    for (int i = tid; i < 2048; i += 512) ((uint4*)hbuf)[i] = make_uint4(0, 0, 0, 0);
    __syncthreads();

    const int grow = tid >> 5, guc = tid & 31;    // gather/publish unit coords
    const int gswz = (grow & 7) << 4;

    for (int t = 0; t < TT; ++t) {
        const int p = t & 1;

        // prefetch w terms (independent of h)
        float wa_[4], wz_[4];
        #pragma unroll
        for (int r = 0; r < 4; ++r) {
            const int b2 = d * 16 + lg * 4 + r;
            const float* wp = w + ((size_t)t * B2 + b2) * G2 + jcol;
            wa_[r] = wp[0];
            wz_[r] = wp[HH];
        }

        if (t > 0) {
            // per-wave poll: lanes 0..3 watch this group's 4 member flags (==8)
            {
                const unsigned int* fl = flags +
                    ((size_t)(t - 1) * 8 + d * 4) * FLAG_STRIDE;
                unsigned v = 8u;
                do {
                    if (l < 4)
                        v = __hip_atomic_load(fl + l * FLAG_STRIDE, __ATOMIC_RELAXED,
                                              __HIP_MEMORY_SCOPE_AGENT);
                    if (__any(v < 8u)) __builtin_amdgcn_s_sleep(1); else break;
                } while (true);
            }
            // burst gather: 3 foreign slices, 8B/thread/slice (all 512 threads)
            const u64* src = hx_d + (size_t)(p ^ 1) * 2048;
            u64 vv[3];
            #pragma unroll
            for (int i = 0; i < 3; ++i) {
                const int sw = i + (i >= q);
                vv[i] = __hip_atomic_load(src + sw * 512 + grow * 32 + guc,
                                          __ATOMIC_RELAXED, __HIP_MEMORY_SCOPE_AGENT);
            }
            char* db = hbuf[p] + grow * 1024;
            #pragma unroll
            for (int i = 0; i < 3; ++i) {
                const int sw = i + (i >= q);
                *(u64*)(db + ((sw * 256 + guc * 8) ^ gswz)) = vv[i];
            }
            __syncthreads();   // (G) gather complete
        }

        // ---- MFMA: a/z 16x16 tiles over K=512 from hbuf[p] ----
        f32x4 aacc = {0.f, 0.f, 0.f, 0.f};
        f32x4 zacc = {0.f, 0.f, 0.f, 0.f};
        const int arow = l15;                   // batch row within group
        const char* rbase = hbuf[p] + arow * 1024;
        const int swz = (arow & 7) << 4;
        #pragma unroll
        for (int ks = 0; ks < 16; ++ks) {
            const int off0 = ks * 64 + lg * 8;
            bf16x4 h0 = *(const bf16x4*)(rbase + (off0 ^ swz));
            bf16x4 h1 = *(const bf16x4*)(rbase + ((off0 + 32) ^ swz));
            bf16x8 af;
            af[0] = h0[0]; af[1] = h0[1]; af[2] = h0[2]; af[3] = h0[3];
            af[4] = h1[0]; af[5] = h1[1]; af[6] = h1[2]; af[7] = h1[3];
            aacc = __builtin_amdgcn_mfma_f32_16x16x32_bf16(af, bfa[ks], aacc, 0, 0, 0);
            zacc = __builtin_amdgcn_mfma_f32_16x16x32_bf16(af, bfz[ks], zacc, 0, 0, 0);
        }

        // ---- gate update; gates -> LDS only (outputs deferred) ----
        float hn4[4];
        #pragma unroll
        for (int r = 0; r < 4; ++r) {
            const int b = lg * 4 + r;           // row within group
            const float aval = scl_a * wa_[r] + sh_a + aacc[r];
            const float zval = scl_z * wz_[r] + sh_z + zacc[r];
            const float zt = 1.f / (1.f + __expf(-zval));
            const float hn = zt * hold[r] + (1.f - zt) * fmaxf(aval, 0.f);
            hold[r] = hn; hn4[r] = hn;
            if (t < TT - 1)
                *(unsigned short*)(hbuf[p ^ 1] + b * 1024 +
                                   ((jcol * 2) ^ ((b & 7) << 4))) = f2bf(hn);
        }

        if (t < TT - 1) {
            __syncthreads();   // (c1) gate LDS writes complete
            // cooperative own-slice publish: 512 x 8B agent stores, then
            // PER-WAVE release: own vmcnt drain + lane-0 flag add (no c2).
            {
                const u64 v = *(const u64*)(hbuf[p ^ 1] + grow * 1024 +
                                            ((256 * q + guc * 8) ^ gswz));
                __hip_atomic_store(hx_d + (size_t)p * 2048 + q * 512 + grow * 32 + guc,
                                   v, __ATOMIC_RELAXED, __HIP_MEMORY_SCOPE_AGENT);
            }
            __builtin_amdgcn_sched_barrier(0);
            asm volatile("s_waitcnt vmcnt(0)" ::: "memory");
            __builtin_amdgcn_sched_barrier(0);
            if (l == 0)
                __hip_atomic_fetch_add(flags + ((size_t)t * 8 + d * 4 + q) * FLAG_STRIDE,
                                       1u, __ATOMIC_RELAXED, __HIP_MEMORY_SCOPE_AGENT);
            __builtin_amdgcn_sched_barrier(0);
        }

        // ---- fused outputs (issued AFTER release: off the critical path) ----
        #pragma unroll
        for (int r = 0; r < 4; ++r) {
            const int b  = lg * 4 + r;
            const int b2 = d * 16 + b;
            const float hn = hn4[r];
            if (LAYER == 0) {
                unsigned short* A1 = (unsigned short*)outp;
                const unsigned short hb = f2bf(hn);
                const int cc = jcol + (d == 0 ? 0 : HH);
                const int r1 = t * B2 + b2;
                const int r2 = (TT - 1 - t) * B2 + (d == 0 ? b2 + 16 : b2 - 16);
                A1[(size_t)r1 * G2 + cc] = hb;
                A1[(size_t)r2 * G2 + cc] = hb;
            } else {
                float* po = (float*)outp;
                const int bb = (d == 0) ? b2 : b2 - 16;
                const int tt = (d == 0) ? t : (TT - 1 - t);
                po[((size_t)bb * TT + tt) * G2 + jcol + (d == 0 ? 0 : HH)] = hn;
            }
        }
    }
}

extern "C" void kernel_launch(void* const* d_in, const int* in_sizes, int n_in,
                              void* d_out, int out_size, void* d_ws, size_t ws_size,
                              hipStream_t stream)
{
    const float* x   = (const float*)d_in[0];
    const float* Ww0 = (const float*)d_in[1];
    const float* Wu0 = (const float*)d_in[2];
    const float* g0  = (const float*)d_in[3];
    const float* b0  = (const float*)d_in[4];
    const float* Ww1 = (const float*)d_in[5];
    const float* Wu1 = (const float*)d_in[6];
    const float* g1  = (const float*)d_in[7];
    const float* b1  = (const float*)d_in[8];
    float* out = (float*)d_out;

    float* w     = (float*)d_ws;                         // 16000*1024 fp32
    float* scr0  = w + (size_t)MROWS * G2;               // 32.77MB scratch (A0b, Wwb)
    float* scr1  = scr0 + (size_t)TT * B2 * HH;          // 32.77MB scratch (A1b)
    float* partS = scr1 + (size_t)TT * B2 * HH;          // 125*1024
    float* partQ = partS + 125 * G2;
    float* scale = partQ + 125 * G2;                     // 1024
    float* shift = scale + G2;
    unsigned int* flags = (unsigned int*)(shift + G2);   // 2 layers x 64000 u32
    u64* hx0 = (u64*)(flags + 2 * FLAGS_PER_LAYER);      // 8192 u64 (layer 0)
    u64* hx1 = hx0 + 8192;                               // 8192 u64 (layer 1)

    unsigned short* A0b = (unsigned short*)scr0;                    // 16000x256 bf16
    unsigned short* Wwb = (unsigned short*)(scr0 + 3 * 1024 * 1024); // 1024x1024 bf16 @ +12MB
    unsigned short* A1b = (unsigned short*)scr1;                    // 16000x1024 bf16

    const size_t needed = ((size_t)MROWS * G2 + 2 * (size_t)TT * B2 * HH +
                           2 * 125 * G2 + 2 * G2) * 4 +
                          (size_t)2 * FLAGS_PER_LAYER * 4 + 16384 * 8;
    if (ws_size < needed) return;

    zero_cnt<<<2 * FLAGS_PER_LAYER / 256, 256, 0, stream>>>(flags);

    // ---- layer 0 ----
    cvt_a0<<<2000, 256, 0, stream>>>(x, A0b);
    cvt_pad<240, 256><<<128, 256, 0, stream>>>(Ww0, Wwb);
    mfma_gemm<256><<<dim3(125, 8), 256, 0, stream>>>(A0b, Wwb, w);
    stats_partial<<<dim3(4, 125), 256, 0, stream>>>(w, partS, partQ);
    stats_final<<<4, 256, 0, stream>>>(partS, partQ, g0, b0, scale, shift);
    rec_kernel<0><<<REC_WGS, 512, 0, stream>>>(w, scale, shift, Wu0, A1b, hx0, flags);

    // ---- layer 1 ----
    cvt_pad<1024, 1024><<<512, 256, 0, stream>>>(Ww1, Wwb);
    mfma_gemm<1024><<<dim3(125, 8), 256, 0, stream>>>(A1b, Wwb, w);
    stats_partial<<<dim3(4, 125), 256, 0, stream>>>(w, partS, partQ);
    stats_final<<<4, 256, 0, stream>>>(partS, partQ, g1, b1, scale, shift);
    rec_kernel<1><<<REC_WGS, 512, 0, stream>>>(w, scale, shift, Wu1, out, hx1,
                                               flags + FLAGS_PER_LAYER);
}

// Round 18
// 2467.050 us; speedup vs baseline: 1.1829x; 1.1829x over previous
//
#include <hip/hip_runtime.h>
#include <math.h>
#include <stdint.h>

#define TT 500
#define B2 32
#define FF 240
#define HH 512
#define G2 1024
#define MROWS (TT*B2)   // 16000
#define REC_WGS 8
// flags: one u32 per (step, group, member), strided 16 u32 (64B)
#define FLAG_STRIDE 16
#define FLAGS_PER_LAYER (TT*8*FLAG_STRIDE)

typedef __attribute__((ext_vector_type(8))) short bf16x8;
typedef __attribute__((ext_vector_type(4))) short bf16x4;
typedef __attribute__((ext_vector_type(4))) float f32x4;
typedef unsigned long long u64;

typedef __attribute__((address_space(1))) const unsigned int GU32;
typedef __attribute__((address_space(3))) unsigned int LU32;

static __device__ __forceinline__ unsigned short f2bf(float f) {
    union { float f; unsigned u; } v; v.f = f;
    unsigned r = v.u + 0x7FFFu + ((v.u >> 16) & 1u);
    return (unsigned short)(r >> 16);
}

static __device__ __forceinline__ void gload_lds16(const void* g, void* l) {
    __builtin_amdgcn_global_load_lds((GU32*)g, (LU32*)l, 16, 0, 0);
}

// ---------------- zero flags ----------------
__global__ void zero_cnt(unsigned int* cnt) {
    cnt[blockIdx.x * 256 + threadIdx.x] = 0u;
}

// ---------------- conversion kernels ----------------
// x (B,T,F) fp32 -> A0 bf16 [16000][256] with x2 gather, zero-pad K 240->256
__global__ __launch_bounds__(256)
void cvt_a0(const float* __restrict__ x, unsigned short* __restrict__ A0)
{
    const int idx = blockIdx.x * 256 + threadIdx.x;   // 512000
    const int m = idx >> 5;
    const int k = (idx & 31) * 8;
    const int t = m >> 5, b2 = m & 31;
    bf16x8 o = {0,0,0,0,0,0,0,0};
    if (k < FF) {
        const float* p = (b2 < 16)
            ? x + ((size_t)(b2 * TT + t)) * FF + k
            : x + ((size_t)((b2 - 16) * TT + (TT - 1 - t))) * FF + k;
        f32x4 a = *(const f32x4*)p;
        f32x4 b = *(const f32x4*)(p + 4);
        #pragma unroll
        for (int j = 0; j < 4; ++j) { o[j] = (short)f2bf(a[j]); o[4+j] = (short)f2bf(b[j]); }
    }
    *(bf16x8*)(A0 + (size_t)m * 256 + k) = o;
}

// Ww fp32 [R][Kin] -> bf16 [R][Kout], zero-pad
template<int Kin, int Kout>
__global__ __launch_bounds__(256)
void cvt_pad(const float* __restrict__ src, unsigned short* __restrict__ dst)
{
    const int idx = blockIdx.x * 256 + threadIdx.x;
    const int r = idx / (Kout / 8);
    const int k = (idx % (Kout / 8)) * 8;
    bf16x8 o = {0,0,0,0,0,0,0,0};
    if (k + 8 <= Kin) {
        f32x4 a = *(const f32x4*)(src + (size_t)r * Kin + k);
        f32x4 b = *(const f32x4*)(src + (size_t)r * Kin + k + 4);
        #pragma unroll
        for (int j = 0; j < 4; ++j) { o[j] = (short)f2bf(a[j]); o[4+j] = (short)f2bf(b[j]); }
    }
    *(bf16x8*)(dst + (size_t)r * Kout + k) = o;
}

// ---------------- MFMA GEMM: C[m][n] = sum_k A[m][k]*B[n][k], C fp32 [M][1024] ----------------
template<int K>
__global__ __launch_bounds__(256, 2)
void mfma_gemm(const unsigned short* __restrict__ A,
               const unsigned short* __restrict__ B,
               float* __restrict__ C)
{
    __shared__ alignas(16) char As[16384];
    __shared__ alignas(16) char Bs[16384];
    const int tid = threadIdx.x;
    const int wv = tid >> 6, l = tid & 63, l15 = l & 15, lg = l >> 4;
    const int m0 = blockIdx.x * 128, n0 = blockIdx.y * 128;
    const int wr = wv >> 1, wc = wv & 1;
    f32x4 acc[4][4];
    #pragma unroll
    for (int i = 0; i < 4; ++i)
        #pragma unroll
        for (int j = 0; j < 4; ++j) acc[i][j] = (f32x4){0.f, 0.f, 0.f, 0.f};

    for (int ko = 0; ko < K; ko += 64) {
        #pragma unroll
        for (int i = 0; i < 4; ++i) {
            const int ch = tid + i * 256;          // 0..1023
            const int row = ch >> 3, q = ch & 7;
            const int kb = (q * 16) ^ ((row & 7) << 4);   // byte offset, pre-swizzled source
            gload_lds16(A + (size_t)(m0 + row) * K + ko + (kb >> 1), As + ch * 16);
            gload_lds16(B + (size_t)(n0 + row) * K + ko + (kb >> 1), Bs + ch * 16);
        }
        __syncthreads();
        #pragma unroll
        for (int ks = 0; ks < 2; ++ks) {
            bf16x8 af[4], bf[4];
            #pragma unroll
            for (int ib = 0; ib < 4; ++ib) {
                const int r = wr * 64 + ib * 16 + l15;
                const int sz = (r & 7) << 4;
                const int kb0 = ks * 64 + lg * 8;
                bf16x4 lo = *(const bf16x4*)(As + r * 128 + (kb0 ^ sz));
                bf16x4 hi = *(const bf16x4*)(As + r * 128 + ((kb0 + 32) ^ sz));
                bf16x8 f;
                f[0]=lo[0]; f[1]=lo[1]; f[2]=lo[2]; f[3]=lo[3];
                f[4]=hi[0]; f[5]=hi[1]; f[6]=hi[2]; f[7]=hi[3];
                af[ib] = f;
            }
            #pragma unroll
            for (int jb = 0; jb < 4; ++jb) {
                const int r = wc * 64 + jb * 16 + l15;
                const int sz = (r & 7) << 4;
                const int kb0 = ks * 64 + lg * 8;
                bf16x4 lo = *(const bf16x4*)(Bs + r * 128 + (kb0 ^ sz));
                bf16x4 hi = *(const bf16x4*)(Bs + r * 128 + ((kb0 + 32) ^ sz));
                bf16x8 f;
                f[0]=lo[0]; f[1]=lo[1]; f[2]=lo[2]; f[3]=lo[3];
                f[4]=hi[0]; f[5]=hi[1]; f[6]=hi[2]; f[7]=hi[3];
                bf[jb] = f;
            }
            #pragma unroll
            for (int ib = 0; ib < 4; ++ib)
                #pragma unroll
                for (int jb = 0; jb < 4; ++jb)
                    acc[ib][jb] = __builtin_amdgcn_mfma_f32_16x16x32_bf16(af[ib], bf[jb], acc[ib][jb], 0, 0, 0);
        }
        __syncthreads();
    }
    #pragma unroll
    for (int ib = 0; ib < 4; ++ib)
        #pragma unroll
        for (int jb = 0; jb < 4; ++jb)
            #pragma unroll
            for (int rr = 0; rr < 4; ++rr)
                C[(size_t)(m0 + wr * 64 + ib * 16 + lg * 4 + rr) * G2 +
                  (n0 + wc * 64 + jb * 16 + l15)] = acc[ib][jb][rr];
}

// ---------------- BatchNorm stats ----------------
__global__ __launch_bounds__(256)
void stats_partial(const float* __restrict__ w, float* __restrict__ partS,
                   float* __restrict__ partQ)
{
    const int col = blockIdx.x * 256 + threadIdx.x;
    const int row0 = blockIdx.y * 128;
    float s = 0.f, q = 0.f;
    for (int r = 0; r < 128; ++r) {
        float v = w[(size_t)(row0 + r) * G2 + col];
        s += v; q += v * v;
    }
    partS[blockIdx.y * G2 + col] = s;
    partQ[blockIdx.y * G2 + col] = q;
}

__global__ __launch_bounds__(256)
void stats_final(const float* __restrict__ partS, const float* __restrict__ partQ,
                 const float* __restrict__ gamma, const float* __restrict__ beta,
                 float* __restrict__ scale, float* __restrict__ shift)
{
    const int col = blockIdx.x * 256 + threadIdx.x;
    float s = 0.f, q = 0.f;
    for (int i = 0; i < 125; ++i) { s += partS[i * G2 + col]; q += partQ[i * G2 + col]; }
    const float mean = s * (1.f / 16000.f);
    float var = q * (1.f / 16000.f) - mean * mean;
    var = fmaxf(var, 0.f);
    const float sc = gamma[col] * rsqrtf(var + 1e-5f);
    scale[col] = sc;
    shift[col] = beta[col] - mean * sc;
}

// ---------------- persistent MFMA recurrence: 2 independent groups x 4 WGs ----------------
// R16 configuration (measured best): flags + burst gather, 4 participants per
// group, c1+c2 barriers with single tid0 flag-RMW, fused outputs issued after
// the flag so their ACKs drain lazily at the next step's c2.
template<int LAYER>
__global__ __launch_bounds__(512, 2)
void rec_kernel(const float* __restrict__ w, const float* __restrict__ scale,
                const float* __restrict__ shift, const float* __restrict__ Wu,
                void* __restrict__ outp, u64* __restrict__ hx,
                unsigned int* __restrict__ flags)
{
    __shared__ alignas(16) char hbuf[2][16384];   // ping-pong h: 16 rows x 1024B, swizzled

    const int g   = blockIdx.x;               // 0..7
    const int d   = g >> 2;                   // group (0 fwd, 1 bwd)
    const int q   = g & 3;                    // member in group
    const int tid = threadIdx.x;
    const int wv  = tid >> 6;
    const int l   = tid & 63;
    const int l15 = l & 15;
    const int lg  = l >> 4;
    const int jcol = 128 * q + 16 * wv + l15; // h column in [128q, 128q+128)

    u64* hx_d = hx + (size_t)d * 4096;        // group region: 2 slots x 2048 u64

    // ---- preload Wu as bf16 B-fragments (k = ks*32 + lg*4 + j, +16 for hi) ----
    bf16x8 bfa[16], bfz[16];
    {
        const float* pa = Wu + (size_t)jcol * HH;
        const float* pz = Wu + (size_t)(HH + jcol) * HH;
        #pragma unroll
        for (int ks = 0; ks < 16; ++ks) {
            f32x4 a0 = *(const f32x4*)(pa + ks * 32 + lg * 4);
            f32x4 a1 = *(const f32x4*)(pa + ks * 32 + lg * 4 + 16);
            f32x4 z0 = *(const f32x4*)(pz + ks * 32 + lg * 4);
            f32x4 z1 = *(const f32x4*)(pz + ks * 32 + lg * 4 + 16);
            bf16x8 fa, fz;
            #pragma unroll
            for (int j = 0; j < 4; ++j) {
                fa[j]     = (short)f2bf(a0[j]);
                fa[4 + j] = (short)f2bf(a1[j]);
                fz[j]     = (short)f2bf(z0[j]);
                fz[4 + j] = (short)f2bf(z1[j]);
            }
            bfa[ks] = fa; bfz[ks] = fz;
        }
    }
    const float scl_a = scale[jcol],      sh_a = shift[jcol];
    const float scl_z = scale[HH + jcol], sh_z = shift[HH + jcol];

    float hold[4] = {0.f, 0.f, 0.f, 0.f};

    for (int i = tid; i < 2048; i += 512) ((uint4*)hbuf)[i] = make_uint4(0, 0, 0, 0);
    __syncthreads();

    const int grow = tid >> 5, guc = tid & 31;    // gather/publish unit coords
    const int gswz = (grow & 7) << 4;

    for (int t = 0; t < TT; ++t) {
        const int p = t & 1;

        // prefetch w terms (independent of h)
        float wa_[4], wz_[4];
        #pragma unroll
        for (int r = 0; r < 4; ++r) {
            const int b2 = d * 16 + lg * 4 + r;
            const float* wp = w + ((size_t)t * B2 + b2) * G2 + jcol;
            wa_[r] = wp[0];
            wz_[r] = wp[HH];
        }

        if (t > 0) {
            // per-wave poll: lanes 0..3 watch this group's 4 member flags
            {
                const unsigned int* fl = flags +
                    ((size_t)(t - 1) * 8 + d * 4) * FLAG_STRIDE;
                unsigned v = 1u;
                do {
                    if (l < 4)
                        v = __hip_atomic_load(fl + l * FLAG_STRIDE, __ATOMIC_RELAXED,
                                              __HIP_MEMORY_SCOPE_AGENT);
                    if (__any(v == 0u)) __builtin_amdgcn_s_sleep(1); else break;
                } while (true);
            }
            // burst gather: 3 foreign slices, 8B/thread/slice (all 512 threads)
            const u64* src = hx_d + (size_t)(p ^ 1) * 2048;
            u64 vv[3];
            #pragma unroll
            for (int i = 0; i < 3; ++i) {
                const int sw = i + (i >= q);
                vv[i] = __hip_atomic_load(src + sw * 512 + grow * 32 + guc,
                                          __ATOMIC_RELAXED, __HIP_MEMORY_SCOPE_AGENT);
            }
            char* db = hbuf[p] + grow * 1024;
            #pragma unroll
            for (int i = 0; i < 3; ++i) {
                const int sw = i + (i >= q);
                *(u64*)(db + ((sw * 256 + guc * 8) ^ gswz)) = vv[i];
            }
            __syncthreads();   // (G) gather complete
        }

        // ---- MFMA: a/z 16x16 tiles over K=512 from hbuf[p] ----
        f32x4 aacc = {0.f, 0.f, 0.f, 0.f};
        f32x4 zacc = {0.f, 0.f, 0.f, 0.f};
        const int arow = l15;                   // batch row within group
        const char* rbase = hbuf[p] + arow * 1024;
        const int swz = (arow & 7) << 4;
        #pragma unroll
        for (int ks = 0; ks < 16; ++ks) {
            const int off0 = ks * 64 + lg * 8;
            bf16x4 h0 = *(const bf16x4*)(rbase + (off0 ^ swz));
            bf16x4 h1 = *(const bf16x4*)(rbase + ((off0 + 32) ^ swz));
            bf16x8 af;
            af[0] = h0[0]; af[1] = h0[1]; af[2] = h0[2]; af[3] = h0[3];
            af[4] = h1[0]; af[5] = h1[1]; af[6] = h1[2]; af[7] = h1[3];
            aacc = __builtin_amdgcn_mfma_f32_16x16x32_bf16(af, bfa[ks], aacc, 0, 0, 0);
            zacc = __builtin_amdgcn_mfma_f32_16x16x32_bf16(af, bfz[ks], zacc, 0, 0, 0);
        }

        // ---- gate update; gates -> LDS only (outputs deferred) ----
        float hn4[4];
        #pragma unroll
        for (int r = 0; r < 4; ++r) {
            const int b = lg * 4 + r;           // row within group
            const float aval = scl_a * wa_[r] + sh_a + aacc[r];
            const float zval = scl_z * wz_[r] + sh_z + zacc[r];
            const float zt = 1.f / (1.f + __expf(-zval));
            const float hn = zt * hold[r] + (1.f - zt) * fmaxf(aval, 0.f);
            hold[r] = hn; hn4[r] = hn;
            if (t < TT - 1)
                *(unsigned short*)(hbuf[p ^ 1] + b * 1024 +
                                   ((jcol * 2) ^ ((b & 7) << 4))) = f2bf(hn);
        }

        if (t < TT - 1) {
            __syncthreads();   // (c1) gate LDS writes complete
            // cooperative own-slice publish: 512 x 8B agent stores
            {
                const u64 v = *(const u64*)(hbuf[p ^ 1] + grow * 1024 +
                                            ((256 * q + guc * 8) ^ gswz));
                __hip_atomic_store(hx_d + (size_t)p * 2048 + q * 512 + grow * 32 + guc,
                                   v, __ATOMIC_RELAXED, __HIP_MEMORY_SCOPE_AGENT);
            }
            __syncthreads();   // (c2) drains vmcnt: publish stores at IC
            if (tid == 0)
                __hip_atomic_fetch_add(flags + ((size_t)t * 8 + d * 4 + q) * FLAG_STRIDE,
                                       1u, __ATOMIC_RELAXED, __HIP_MEMORY_SCOPE_AGENT);
        }

        // ---- fused outputs (issued AFTER flag: off the publish critical path,
        //      drained lazily by the NEXT step's c2) ----
        #pragma unroll
        for (int r = 0; r < 4; ++r) {
            const int b  = lg * 4 + r;
            const int b2 = d * 16 + b;
            const float hn = hn4[r];
            if (LAYER == 0) {
                unsigned short* A1 = (unsigned short*)outp;
                const unsigned short hb = f2bf(hn);
                const int cc = jcol + (d == 0 ? 0 : HH);
                const int r1 = t * B2 + b2;
                const int r2 = (TT - 1 - t) * B2 + (d == 0 ? b2 + 16 : b2 - 16);
                A1[(size_t)r1 * G2 + cc] = hb;
                A1[(size_t)r2 * G2 + cc] = hb;
            } else {
                float* po = (float*)outp;
                const int bb = (d == 0) ? b2 : b2 - 16;
                const int tt = (d == 0) ? t : (TT - 1 - t);
                po[((size_t)bb * TT + tt) * G2 + jcol + (d == 0 ? 0 : HH)] = hn;
            }
        }
    }
}

extern "C" void kernel_launch(void* const* d_in, const int* in_sizes, int n_in,
                              void* d_out, int out_size, void* d_ws, size_t ws_size,
                              hipStream_t stream)
{
    const float* x   = (const float*)d_in[0];
    const float* Ww0 = (const float*)d_in[1];
    const float* Wu0 = (const float*)d_in[2];
    const float* g0  = (const float*)d_in[3];
    const float* b0  = (const float*)d_in[4];
    const float* Ww1 = (const float*)d_in[5];
    const float* Wu1 = (const float*)d_in[6];
    const float* g1  = (const float*)d_in[7];
    const float* b1  = (const float*)d_in[8];
    float* out = (float*)d_out;

    float* w     = (float*)d_ws;                         // 16000*1024 fp32
    float* scr0  = w + (size_t)MROWS * G2;               // 32.77MB scratch (A0b, Wwb)
    float* scr1  = scr0 + (size_t)TT * B2 * HH;          // 32.77MB scratch (A1b)
    float* partS = scr1 + (size_t)TT * B2 * HH;          // 125*1024
    float* partQ = partS + 125 * G2;
    float* scale = partQ + 125 * G2;                     // 1024
    float* shift = scale + G2;
    unsigned int* flags = (unsigned int*)(shift + G2);   // 2 layers x 64000 u32
    u64* hx0 = (u64*)(flags + 2 * FLAGS_PER_LAYER);      // 8192 u64 (layer 0)
    u64* hx1 = hx0 + 8192;                               // 8192 u64 (layer 1)

    unsigned short* A0b = (unsigned short*)scr0;                    // 16000x256 bf16
    unsigned short* Wwb = (unsigned short*)(scr0 + 3 * 1024 * 1024); // 1024x1024 bf16 @ +12MB
    unsigned short* A1b = (unsigned short*)scr1;                    // 16000x1024 bf16

    const size_t needed = ((size_t)MROWS * G2 + 2 * (size_t)TT * B2 * HH +
                           2 * 125 * G2 + 2 * G2) * 4 +
                          (size_t)2 * FLAGS_PER_LAYER * 4 + 16384 * 8;
    if (ws_size < needed) return;

    zero_cnt<<<2 * FLAGS_PER_LAYER / 256, 256, 0, stream>>>(flags);

    // ---- layer 0 ----
    cvt_a0<<<2000, 256, 0, stream>>>(x, A0b);
    cvt_pad<240, 256><<<128, 256, 0, stream>>>(Ww0, Wwb);
    mfma_gemm<256><<<dim3(125, 8), 256, 0, stream>>>(A0b, Wwb, w);
    stats_partial<<<dim3(4, 125), 256, 0, stream>>>(w, partS, partQ);
    stats_final<<<4, 256, 0, stream>>>(partS, partQ, g0, b0, scale, shift);
    rec_kernel<0><<<REC_WGS, 512, 0, stream>>>(w, scale, shift, Wu0, A1b, hx0, flags);

    // ---- layer 1 ----
    cvt_pad<1024, 1024><<<512, 256, 0, stream>>>(Ww1, Wwb);
    mfma_gemm<1024><<<dim3(125, 8), 256, 0, stream>>>(A1b, Wwb, w);
    stats_partial<<<dim3(4, 125), 256, 0, stream>>>(w, partS, partQ);
    stats_final<<<4, 256, 0, stream>>>(partS, partQ, g1, b1, scale, shift);
    rec_kernel<1><<<REC_WGS, 512, 0, stream>>>(w, scale, shift, Wu1, out, hx1,
                                               flags + FLAGS_PER_LAYER);
}